// Round 10
// baseline (170.827 us; speedup 1.0000x reference)
//
#include <hip/hip_runtime.h>

typedef short bf16x8 __attribute__((ext_vector_type(8)));
typedef float f32x4 __attribute__((ext_vector_type(4)));

__device__ __forceinline__ float b2f(unsigned short s) {
    union { float f; unsigned u; } x; x.u = ((unsigned)s) << 16; return x.f;
}
__device__ __forceinline__ unsigned short f2b(float f) {
    unsigned u = __float_as_uint(f);
    unsigned r = (u + 0x7fffu + ((u >> 16) & 1u)) >> 16;
    return (unsigned short)r;
}

// ---------------- cast f32 weights -> bf16 workspace; zero window counters ----------------
// dst layout: [ciw 32768][qw 49152][pw 16384][ow 16384][cw 32768]  (147456 = 576*256)
__global__ __launch_bounds__(256) void cast_k(const float* __restrict__ ciw,
                                              const float* __restrict__ qw,
                                              const float* __restrict__ pw,
                                              const float* __restrict__ ow,
                                              const float* __restrict__ cw,
                                              unsigned short* __restrict__ dst,
                                              int* __restrict__ cnt) {
    if (blockIdx.x == 0 && threadIdx.x < 128) cnt[threadIdx.x] = 0;
    int i = blockIdx.x * 256 + threadIdx.x;
    float v;
    if (i < 32768)        v = ciw[i];
    else if (i < 81920)   v = qw[i - 32768];
    else if (i < 98304)   v = pw[i - 81920];
    else if (i < 114688)  v = ow[i - 98304];
    else                  v = cw[i - 114688];
    dst[i] = f2b(v);
}

// ---------------- window bookkeeping ----------------
__global__ __launch_bounds__(256) void assign_k(const int* __restrict__ uv,
                                                int* __restrict__ cnt,
                                                int* __restrict__ wpts) {
    int i = blockIdx.x * 256 + threadIdx.x;
    if (i >= 8192) return;
    int b = uv[3 * i] & 1;
    int u = uv[3 * i + 1] & 63;
    int v = uv[3 * i + 2] & 63;
    int w = b * 64 + ((v >> 3) << 3) + (u >> 3);
    int slot = atomicAdd(cnt + w, 1);
    if (slot < 192) wpts[w * 192 + slot] = i;
}

// ---------------- fused conv_in: transpose(in) @ ciw^T + bias -> feat (bf16) ----------------
// 128 blocks x 256 thr (4 waves). Block owns 64 pixels x all 128 outputs, K=256.
// Phase 1: two-step LDS transpose (t tile) builds At[p][c] bf16. Phase 2: MFMA GEMM.
// NOTE: p0 is the GLOBAL token index (includes b*4096); the image read uses hw0 = p0&4095.
__global__ __launch_bounds__(256) void cin_k(const float* __restrict__ in,
                                             const unsigned short* __restrict__ Wm,
                                             const float* __restrict__ bias,
                                             unsigned short* __restrict__ feat) {
    __shared__ unsigned short t[64][65];
    __shared__ unsigned short At[64][264];
    int p0 = blockIdx.x * 64, b = p0 >> 12, hw0 = p0 & 4095;
    int lane = threadIdx.x & 63, quad = threadIdx.x >> 6;
    for (int j = 0; j < 4; ++j) {
        int c0 = j * 64;
#pragma unroll
        for (int i = 0; i < 16; ++i) {
            int c = quad + i * 4;
            t[c][lane] = f2b(in[((size_t)(b * 256 + c0 + c)) * 4096 + hw0 + lane]);
        }
        __syncthreads();
#pragma unroll
        for (int i = 0; i < 16; ++i) {
            int p = quad + i * 4;
            At[p][c0 + lane] = t[lane][p];
        }
        __syncthreads();
    }
    int q = lane & 15, g = lane >> 4;
    int m0 = quad * 16;
    f32x4 acc[8];
#pragma unroll
    for (int tn = 0; tn < 8; ++tn) acc[tn] = (f32x4){0.f, 0.f, 0.f, 0.f};
#pragma unroll
    for (int k0 = 0; k0 < 256; k0 += 32) {
        bf16x8 a = *(const bf16x8*)&At[m0 + q][k0 + g * 8];
#pragma unroll
        for (int tn = 0; tn < 8; ++tn) {
            bf16x8 bfr = *(const bf16x8*)(Wm + (size_t)(tn * 16 + q) * 256 + k0 + g * 8);
            acc[tn] = __builtin_amdgcn_mfma_f32_16x16x32_bf16(a, bfr, acc[tn], 0, 0, 0);
        }
    }
#pragma unroll
    for (int tn = 0; tn < 8; ++tn) {
        int n = tn * 16 + q;
        float bs = bias[n];
#pragma unroll
        for (int rr = 0; rr < 4; ++rr)
            feat[(size_t)(p0 + m0 + g * 4 + rr) * 128 + n] = f2b(acc[tn][rr] + bs);
    }
}

// ---------------- qkv GEMM: rows<8192 from feat (bf16), rows>=8192 from ptsf (f32 inline) ----
__global__ __launch_bounds__(256) void qkv_k(const unsigned short* __restrict__ feat,
                                             const float* __restrict__ ptsf,
                                             const unsigned short* __restrict__ Wm,
                                             const float* __restrict__ bias,
                                             unsigned short* __restrict__ qkv) {
    int lane = threadIdx.x & 63, wv = threadIdx.x >> 6;
    int m0 = (blockIdx.x * 4 + wv) * 16;
    int q = lane & 15, g = lane >> 4;
    int nb = blockIdx.y * 64, koff = g * 8;
    bool isPt = m0 >= 8192;
    f32x4 acc[4];
#pragma unroll
    for (int tt = 0; tt < 4; ++tt) acc[tt] = (f32x4){0.f, 0.f, 0.f, 0.f};
#pragma unroll
    for (int k0 = 0; k0 < 128; k0 += 32) {
        bf16x8 a;
        if (isPt) {
            const float* pr = ptsf + (size_t)(m0 + q - 8192) * 128 + k0 + koff;
            float4 f0 = *(const float4*)pr;
            float4 f1 = *(const float4*)(pr + 4);
            a[0] = (short)f2b(f0.x); a[1] = (short)f2b(f0.y);
            a[2] = (short)f2b(f0.z); a[3] = (short)f2b(f0.w);
            a[4] = (short)f2b(f1.x); a[5] = (short)f2b(f1.y);
            a[6] = (short)f2b(f1.z); a[7] = (short)f2b(f1.w);
        } else {
            a = *(const bf16x8*)(feat + (size_t)(m0 + q) * 128 + k0 + koff);
        }
#pragma unroll
        for (int tt = 0; tt < 4; ++tt) {
            bf16x8 bfr = *(const bf16x8*)(Wm + (size_t)(nb + tt * 16 + q) * 128 + k0 + koff);
            acc[tt] = __builtin_amdgcn_mfma_f32_16x16x32_bf16(a, bfr, acc[tt], 0, 0, 0);
        }
    }
#pragma unroll
    for (int tt = 0; tt < 4; ++tt) {
        int n = nb + tt * 16 + q;
        float bs = bias[n];
#pragma unroll
        for (int rr = 0; rr < 4; ++rr)
            qkv[(size_t)(m0 + g * 4 + rr) * 384 + n] = f2b(acc[tt][rr] + bs);
    }
}

// ---------------- MFMA windowed attention (verified round 6) ----------------
__global__ __launch_bounds__(256) void attn_k(const unsigned short* __restrict__ qkv,
                                              const int* __restrict__ cnt,
                                              const int* __restrict__ wpts,
                                              unsigned short* __restrict__ aout) {
    __shared__ unsigned short Kl[256][24];
    __shared__ unsigned short Vt[16][264];
    int blk = blockIdx.x;
    int w = blk >> 3, h = blk & 7;
    int b = w >> 6, wy = (w >> 3) & 7, wx = w & 7;
    int tid = threadIdx.x, wave = tid >> 6, lane = tid & 63;
    int q = lane & 15, g = lane >> 4;
    int c = cnt[w]; if (c > 192) c = 192;
    int T = 64 + c;
    {
        int t = tid;
        if (t < T) {
            int tok;
            if (t < 64) tok = b * 4096 + (wy * 8 + (t >> 3)) * 64 + wx * 8 + (t & 7);
            else        tok = 8192 + wpts[w * 192 + t - 64];
            const unsigned short* base = qkv + (size_t)tok * 384 + h * 16;
            bf16x8 k0 = *(const bf16x8*)(base + 128);
            bf16x8 v0 = *(const bf16x8*)(base + 256);
            *(bf16x8*)&Kl[t][0] = k0;
#pragma unroll
            for (int d = 0; d < 8; ++d) Vt[d][t] = (unsigned short)v0[d];
            bf16x8 k1 = *(const bf16x8*)(base + 136);
            bf16x8 v1 = *(const bf16x8*)(base + 264);
            *(bf16x8*)&Kl[t][8] = k1;
#pragma unroll
            for (int d = 0; d < 8; ++d) Vt[8 + d][t] = (unsigned short)v1[d];
        } else {
            bf16x8 z;
#pragma unroll
            for (int d = 0; d < 8; ++d) z[d] = 0;
            *(bf16x8*)&Kl[t][0] = z;
            *(bf16x8*)&Kl[t][8] = z;
#pragma unroll
            for (int d = 0; d < 16; ++d) Vt[d][t] = 0;
        }
    }
    int qq = wave * 16 + q;
    int qrow = b * 4096 + (wy * 8 + (qq >> 3)) * 64 + wx * 8 + (qq & 7);
    bf16x8 qfrag;
#pragma unroll
    for (int j = 0; j < 8; ++j) qfrag[j] = 0;
    if (g < 2) qfrag = *(const bf16x8*)(qkv + (size_t)qrow * 384 + h * 16 + g * 8);

    __syncthreads();

    float p[16][4];
    int MT = (T + 15) >> 4;
#pragma unroll
    for (int mt = 0; mt < 16; ++mt) {
        if (mt < MT) {
            bf16x8 af = *(const bf16x8*)&Kl[mt * 16 + q][(g & 1) * 8];
            f32x4 cc = (f32x4){0.f, 0.f, 0.f, 0.f};
            cc = __builtin_amdgcn_mfma_f32_16x16x32_bf16(af, qfrag, cc, 0, 0, 0);
#pragma unroll
            for (int r = 0; r < 4; ++r) {
                int tok = mt * 16 + g * 4 + r;
                p[mt][r] = (tok < T) ? cc[r] * 0.25f : -1e30f;
            }
        } else {
#pragma unroll
            for (int r = 0; r < 4; ++r) p[mt][r] = -1e30f;
        }
    }
    float mv = -3.0e38f;
#pragma unroll
    for (int mt = 0; mt < 16; ++mt)
#pragma unroll
        for (int r = 0; r < 4; ++r) mv = fmaxf(mv, p[mt][r]);
    mv = fmaxf(mv, __shfl_xor(mv, 16));
    mv = fmaxf(mv, __shfl_xor(mv, 32));
    float ls = 0.f;
#pragma unroll
    for (int mt = 0; mt < 16; ++mt)
#pragma unroll
        for (int r = 0; r < 4; ++r) {
            float e = __expf(p[mt][r] - mv);
            p[mt][r] = e;
            ls += e;
        }
    ls += __shfl_xor(ls, 16);
    ls += __shfl_xor(ls, 32);

    f32x4 oacc = (f32x4){0.f, 0.f, 0.f, 0.f};
    int KS = (T + 31) >> 5;
    int srcA = q + (((2 * g) & 3) << 4);
    int srcB = q + (((2 * g + 1) & 3) << 4);
#pragma unroll
    for (int ks = 0; ks < 8; ++ks) {
        if (ks < KS) {
            int n0lo, n0hi, n1lo, n1hi;
            asm("v_cvt_pk_bf16_f32 %0, %1, %2" : "=v"(n0lo) : "v"(p[2 * ks][0]), "v"(p[2 * ks][1]));
            asm("v_cvt_pk_bf16_f32 %0, %1, %2" : "=v"(n0hi) : "v"(p[2 * ks][2]), "v"(p[2 * ks][3]));
            asm("v_cvt_pk_bf16_f32 %0, %1, %2" : "=v"(n1lo) : "v"(p[2 * ks + 1][0]), "v"(p[2 * ks + 1][1]));
            asm("v_cvt_pk_bf16_f32 %0, %1, %2" : "=v"(n1hi) : "v"(p[2 * ks + 1][2]), "v"(p[2 * ks + 1][3]));
            int a0 = __shfl(n0lo, srcA), b0 = __shfl(n1lo, srcA);
            int a1 = __shfl(n0hi, srcA), b1 = __shfl(n1hi, srcA);
            int a2 = __shfl(n0lo, srcB), b2 = __shfl(n1lo, srcB);
            int a3 = __shfl(n0hi, srcB), b3 = __shfl(n1hi, srcB);
            union { int d[4]; bf16x8 v; } pb;
            bool lo2 = (g < 2);
            pb.d[0] = lo2 ? a0 : b0;
            pb.d[1] = lo2 ? a1 : b1;
            pb.d[2] = lo2 ? a2 : b2;
            pb.d[3] = lo2 ? a3 : b3;
            bf16x8 vf = *(const bf16x8*)&Vt[q][ks * 32 + g * 8];
            oacc = __builtin_amdgcn_mfma_f32_16x16x32_bf16(vf, pb.v, oacc, 0, 0, 0);
        }
    }
    float inv = 1.0f / ls;
    ushort4 st;
    st.x = f2b(oacc[0] * inv);
    st.y = f2b(oacc[1] * inv);
    st.z = f2b(oacc[2] * inv);
    st.w = f2b(oacc[3] * inv);
    *(ushort4*)(aout + (size_t)qrow * 128 + h * 16 + g * 4) = st;
}

// ---------------- fused tail: proj GEMM + RK4 ODE + residual + conv_out ----------------
// 256 blocks x 128 thr (2 waves); wave owns 16 pixel-rows. Proj result stays in the
// C-frag register layout the ODE uses; final (y+y0) goes through tc LDS transpose to
// become the conv_out A operand. Stores f32 bchw directly to d_out.
__global__ __launch_bounds__(128) void tail_k(const unsigned short* __restrict__ aout,
                                              const unsigned short* __restrict__ pwb,
                                              const float* __restrict__ pb,
                                              const unsigned short* __restrict__ owb,
                                              const float* __restrict__ ob,
                                              const unsigned short* __restrict__ cwb,
                                              const float* __restrict__ cb,
                                              float* __restrict__ outp) {
    __shared__ unsigned short Wl[128][136];
    __shared__ unsigned short tc[2][16][136];
    int tid = threadIdx.x, wave = tid >> 6, lane = tid & 63;
    int g = lane >> 4, q = lane & 15;
    {
        int part = tid & 15;
#pragma unroll
        for (int it = 0; it < 16; ++it) {
            int rr = (tid >> 4) + it * 8;
            *(bf16x8*)&Wl[rr][part * 8] = *(const bf16x8*)(owb + rr * 128 + part * 8);
        }
    }
    int R0 = blockIdx.x * 32 + wave * 16;

    // ---- phase A: proj GEMM -> y0 in C-frag layout (row g*4+rr, col tn*16+q) ----
    float y0[32];
    {
        const unsigned short* Arow = aout + (size_t)(R0 + q) * 128;
        f32x4 pacc[8];
#pragma unroll
        for (int tn = 0; tn < 8; ++tn) pacc[tn] = (f32x4){0.f, 0.f, 0.f, 0.f};
#pragma unroll
        for (int k0 = 0; k0 < 128; k0 += 32) {
            bf16x8 a = *(const bf16x8*)(Arow + k0 + g * 8);
#pragma unroll
            for (int tn = 0; tn < 8; ++tn) {
                bf16x8 bfr = *(const bf16x8*)(pwb + (size_t)(tn * 16 + q) * 128 + k0 + g * 8);
                pacc[tn] = __builtin_amdgcn_mfma_f32_16x16x32_bf16(a, bfr, pacc[tn], 0, 0, 0);
            }
        }
#pragma unroll
        for (int tn = 0; tn < 8; ++tn) {
            float bs = pb[tn * 16 + q];
#pragma unroll
            for (int rr = 0; rr < 4; ++rr) y0[tn * 4 + rr] = pacc[tn][rr] + bs;
        }
    }

    float bs[8];
#pragma unroll
    for (int tn = 0; tn < 8; ++tn) bs[tn] = ob[tn * 16 + q];
    float y[32], acc[32], ko[32];
#pragma unroll
    for (int i = 0; i < 32; ++i) y[i] = y0[i];

#define WRITE_TC(EXPR)                                            \
    {                                                             \
        _Pragma("unroll")                                         \
        for (int tn = 0; tn < 8; ++tn) {                          \
            _Pragma("unroll")                                     \
            for (int rr = 0; rr < 4; ++rr) {                      \
                int i_ = tn * 4 + rr;                             \
                tc[wave][g * 4 + rr][tn * 16 + q] = f2b(EXPR);    \
            }                                                     \
        }                                                         \
        __syncthreads();                                          \
    }

#define EVAL()                                                                         \
    {                                                                                  \
        bf16x8 af[4];                                                                  \
        _Pragma("unroll")                                                              \
        for (int tk = 0; tk < 4; ++tk)                                                 \
            af[tk] = *(const bf16x8*)&tc[wave][q][tk * 32 + g * 8];                    \
        _Pragma("unroll")                                                              \
        for (int tn = 0; tn < 8; ++tn) {                                               \
            f32x4 cc = (f32x4){0.f, 0.f, 0.f, 0.f};                                    \
            _Pragma("unroll")                                                          \
            for (int tk = 0; tk < 4; ++tk) {                                           \
                bf16x8 bfr = *(const bf16x8*)&Wl[tn * 16 + q][tk * 32 + g * 8];        \
                cc = __builtin_amdgcn_mfma_f32_16x16x32_bf16(af[tk], bfr, cc, 0, 0, 0);\
            }                                                                          \
            _Pragma("unroll")                                                          \
            for (int rr = 0; rr < 4; ++rr)                                             \
                ko[tn * 4 + rr] = fmaxf(cc[rr] + bs[tn], 0.f);                         \
        }                                                                              \
    }

    WRITE_TC(y[i_])
    const float dt = 0.25f;
    for (int st = 0; st < 4; ++st) {
        EVAL();
#pragma unroll
        for (int i = 0; i < 32; ++i) acc[i] = y[i] + (dt / 6.f) * ko[i];
        WRITE_TC(y[i_] + (0.5f * dt) * ko[i_])
        EVAL();
#pragma unroll
        for (int i = 0; i < 32; ++i) acc[i] += (dt / 3.f) * ko[i];
        WRITE_TC(y[i_] + (0.5f * dt) * ko[i_])
        EVAL();
#pragma unroll
        for (int i = 0; i < 32; ++i) acc[i] += (dt / 3.f) * ko[i];
        WRITE_TC(y[i_] + dt * ko[i_])
        EVAL();
#pragma unroll
        for (int i = 0; i < 32; ++i) y[i] = acc[i] + (dt / 6.f) * ko[i];
        WRITE_TC(y[i_])
    }

    // ---- phase C: residual + conv_out (N=256), A-frags via tc transpose ----
    WRITE_TC(y[i_] + y0[i_])
    {
        int p = R0 + g * 4;
        int bb = p >> 12, plo = p & 4095;
#pragma unroll
        for (int tn2 = 0; tn2 < 16; ++tn2) {
            f32x4 cc = (f32x4){0.f, 0.f, 0.f, 0.f};
#pragma unroll
            for (int tk = 0; tk < 4; ++tk) {
                bf16x8 af = *(const bf16x8*)&tc[wave][q][tk * 32 + g * 8];
                bf16x8 bfr = *(const bf16x8*)(cwb + (size_t)(tn2 * 16 + q) * 128 + tk * 32 + g * 8);
                cc = __builtin_amdgcn_mfma_f32_16x16x32_bf16(af, bfr, cc, 0, 0, 0);
            }
            int ch = tn2 * 16 + q;
            float bsv = cb[ch];
            float4 stv;
            stv.x = cc[0] + bsv;
            stv.y = cc[1] + bsv;
            stv.z = cc[2] + bsv;
            stv.w = cc[3] + bsv;
            *(float4*)(outp + ((size_t)(bb * 256 + ch)) * 4096 + plo) = stv;
        }
    }
#undef WRITE_TC
#undef EVAL
}

extern "C" void kernel_launch(void* const* d_in, const int* in_sizes, int n_in,
                              void* d_out, int out_size, void* d_ws, size_t ws_size,
                              hipStream_t stream) {
    (void)in_sizes; (void)n_in; (void)out_size; (void)ws_size;
    const float* img_in = (const float*)d_in[0];
    const int*   pts_uv = (const int*)d_in[1];
    const float* ptsf   = (const float*)d_in[2];
    const float* ciw    = (const float*)d_in[3];
    const float* cib    = (const float*)d_in[4];
    const float* qw     = (const float*)d_in[5];
    const float* qb     = (const float*)d_in[6];
    const float* pw     = (const float*)d_in[7];
    const float* pb     = (const float*)d_in[8];
    const float* ow     = (const float*)d_in[9];
    const float* ob     = (const float*)d_in[10];
    const float* cw     = (const float*)d_in[11];
    const float* cb     = (const float*)d_in[12];

    char* ws = (char*)d_ws;
    unsigned short* feat = (unsigned short*)(ws);                 // [0,        2097152)  8192x128 bf16
    unsigned short* qkv  = (unsigned short*)(ws + 2097152);       // [2097152, 14680064)  16384x384 bf16
    unsigned short* aout = (unsigned short*)(ws + 14680064);      // [14680064,16777216)  8192x128 bf16
    int*            cnt  = (int*)(ws + 16777216);                 // [16777216,16777728)  128 ints
    int*            wpts = (int*)(ws + 16777728);                 // [16777728,16876032)  128x192 ints
    unsigned short* wb   = (unsigned short*)(ws + 16876544);      // [16876544,17171456)  bf16 weights
    unsigned short* ciw_b = wb;
    unsigned short* qw_b  = wb + 32768;
    unsigned short* pw_b  = wb + 81920;
    unsigned short* ow_b  = wb + 98304;
    unsigned short* cw_b  = wb + 114688;

    cast_k<<<576, 256, 0, stream>>>(ciw, qw, pw, ow, cw, wb, cnt);
    assign_k<<<32, 256, 0, stream>>>(pts_uv, cnt, wpts);
    cin_k<<<128, 256, 0, stream>>>(img_in, ciw_b, cib, feat);
    qkv_k<<<dim3(256, 6), 256, 0, stream>>>(feat, ptsf, qw_b, qb, qkv);
    attn_k<<<1024, 256, 0, stream>>>(qkv, cnt, wpts, aout);
    tail_k<<<256, 128, 0, stream>>>(aout, pw_b, pb, ow_b, ob, cw_b, cb, (float*)d_out);
}

// Round 11
// 153.389 us; speedup vs baseline: 1.1137x; 1.1137x over previous
//
#include <hip/hip_runtime.h>

typedef short bf16x8 __attribute__((ext_vector_type(8)));
typedef float f32x4 __attribute__((ext_vector_type(4)));

__device__ __forceinline__ float b2f(unsigned short s) {
    union { float f; unsigned u; } x; x.u = ((unsigned)s) << 16; return x.f;
}
__device__ __forceinline__ unsigned short f2b(float f) {
    unsigned u = __float_as_uint(f);
    unsigned r = (u + 0x7fffu + ((u >> 16) & 1u)) >> 16;
    return (unsigned short)r;
}

// ---------------- cast f32 weights -> bf16 workspace; zero window counters ----------------
// dst layout: [ciw 32768][qw 49152][pw 16384][ow 16384][cw 32768]  (147456 = 576*256)
__global__ __launch_bounds__(256) void cast_k(const float* __restrict__ ciw,
                                              const float* __restrict__ qw,
                                              const float* __restrict__ pw,
                                              const float* __restrict__ ow,
                                              const float* __restrict__ cw,
                                              unsigned short* __restrict__ dst,
                                              int* __restrict__ cnt) {
    if (blockIdx.x == 0 && threadIdx.x < 128) cnt[threadIdx.x] = 0;
    int i = blockIdx.x * 256 + threadIdx.x;
    float v;
    if (i < 32768)        v = ciw[i];
    else if (i < 81920)   v = qw[i - 32768];
    else if (i < 98304)   v = pw[i - 81920];
    else if (i < 114688)  v = ow[i - 98304];
    else                  v = cw[i - 114688];
    dst[i] = f2b(v);
}

// ---------------- window bookkeeping ----------------
__global__ __launch_bounds__(256) void assign_k(const int* __restrict__ uv,
                                                int* __restrict__ cnt,
                                                int* __restrict__ wpts) {
    int i = blockIdx.x * 256 + threadIdx.x;
    if (i >= 8192) return;
    int b = uv[3 * i] & 1;
    int u = uv[3 * i + 1] & 63;
    int v = uv[3 * i + 2] & 63;
    int w = b * 64 + ((v >> 3) << 3) + (u >> 3);
    int slot = atomicAdd(cnt + w, 1);
    if (slot < 192) wpts[w * 192 + slot] = i;
}

// ---------------- fused conv_in: transpose(in) @ ciw^T + bias -> feat (bf16) ----------------
// 128 blocks x 256 thr (4 waves). Block owns 64 pixels x all 128 outputs, K=256.
// p0 is the GLOBAL token index; the image read uses hw0 = p0&4095 (verified round 10).
__global__ __launch_bounds__(256) void cin_k(const float* __restrict__ in,
                                             const unsigned short* __restrict__ Wm,
                                             const float* __restrict__ bias,
                                             unsigned short* __restrict__ feat) {
    __shared__ unsigned short t[64][65];
    __shared__ unsigned short At[64][264];
    int p0 = blockIdx.x * 64, b = p0 >> 12, hw0 = p0 & 4095;
    int lane = threadIdx.x & 63, quad = threadIdx.x >> 6;
    for (int j = 0; j < 4; ++j) {
        int c0 = j * 64;
#pragma unroll
        for (int i = 0; i < 16; ++i) {
            int c = quad + i * 4;
            t[c][lane] = f2b(in[((size_t)(b * 256 + c0 + c)) * 4096 + hw0 + lane]);
        }
        __syncthreads();
#pragma unroll
        for (int i = 0; i < 16; ++i) {
            int p = quad + i * 4;
            At[p][c0 + lane] = t[lane][p];
        }
        __syncthreads();
    }
    int q = lane & 15, g = lane >> 4;
    int m0 = quad * 16;
    f32x4 acc[8];
#pragma unroll
    for (int tn = 0; tn < 8; ++tn) acc[tn] = (f32x4){0.f, 0.f, 0.f, 0.f};
#pragma unroll
    for (int k0 = 0; k0 < 256; k0 += 32) {
        bf16x8 a = *(const bf16x8*)&At[m0 + q][k0 + g * 8];
#pragma unroll
        for (int tn = 0; tn < 8; ++tn) {
            bf16x8 bfr = *(const bf16x8*)(Wm + (size_t)(tn * 16 + q) * 256 + k0 + g * 8);
            acc[tn] = __builtin_amdgcn_mfma_f32_16x16x32_bf16(a, bfr, acc[tn], 0, 0, 0);
        }
    }
#pragma unroll
    for (int tn = 0; tn < 8; ++tn) {
        int n = tn * 16 + q;
        float bs = bias[n];
#pragma unroll
        for (int rr = 0; rr < 4; ++rr)
            feat[(size_t)(p0 + m0 + g * 4 + rr) * 128 + n] = f2b(acc[tn][rr] + bs);
    }
}

// ---------------- qkv GEMM: rows<8192 from feat (bf16), rows>=8192 from ptsf (f32 inline) ----
// Point rows are never attention queries -> skip their Q columns (nb<128).
__global__ __launch_bounds__(256) void qkv_k(const unsigned short* __restrict__ feat,
                                             const float* __restrict__ ptsf,
                                             const unsigned short* __restrict__ Wm,
                                             const float* __restrict__ bias,
                                             unsigned short* __restrict__ qkv) {
    if (blockIdx.x >= 128 && blockIdx.y < 2) return;  // dead Q tiles of point rows
    int lane = threadIdx.x & 63, wv = threadIdx.x >> 6;
    int m0 = (blockIdx.x * 4 + wv) * 16;
    int q = lane & 15, g = lane >> 4;
    int nb = blockIdx.y * 64, koff = g * 8;
    bool isPt = m0 >= 8192;
    f32x4 acc[4];
#pragma unroll
    for (int tt = 0; tt < 4; ++tt) acc[tt] = (f32x4){0.f, 0.f, 0.f, 0.f};
#pragma unroll
    for (int k0 = 0; k0 < 128; k0 += 32) {
        bf16x8 a;
        if (isPt) {
            const float* pr = ptsf + (size_t)(m0 + q - 8192) * 128 + k0 + koff;
            float4 f0 = *(const float4*)pr;
            float4 f1 = *(const float4*)(pr + 4);
            a[0] = (short)f2b(f0.x); a[1] = (short)f2b(f0.y);
            a[2] = (short)f2b(f0.z); a[3] = (short)f2b(f0.w);
            a[4] = (short)f2b(f1.x); a[5] = (short)f2b(f1.y);
            a[6] = (short)f2b(f1.z); a[7] = (short)f2b(f1.w);
        } else {
            a = *(const bf16x8*)(feat + (size_t)(m0 + q) * 128 + k0 + koff);
        }
#pragma unroll
        for (int tt = 0; tt < 4; ++tt) {
            bf16x8 bfr = *(const bf16x8*)(Wm + (size_t)(nb + tt * 16 + q) * 128 + k0 + koff);
            acc[tt] = __builtin_amdgcn_mfma_f32_16x16x32_bf16(a, bfr, acc[tt], 0, 0, 0);
        }
    }
#pragma unroll
    for (int tt = 0; tt < 4; ++tt) {
        int n = nb + tt * 16 + q;
        float bs = bias[n];
#pragma unroll
        for (int rr = 0; rr < 4; ++rr)
            qkv[(size_t)(m0 + g * 4 + rr) * 384 + n] = f2b(acc[tt][rr] + bs);
    }
}

// ---------------- MFMA windowed attention (verified round 6) ----------------
__global__ __launch_bounds__(256) void attn_k(const unsigned short* __restrict__ qkv,
                                              const int* __restrict__ cnt,
                                              const int* __restrict__ wpts,
                                              unsigned short* __restrict__ aout) {
    __shared__ unsigned short Kl[256][24];
    __shared__ unsigned short Vt[16][264];
    int blk = blockIdx.x;
    int w = blk >> 3, h = blk & 7;
    int b = w >> 6, wy = (w >> 3) & 7, wx = w & 7;
    int tid = threadIdx.x, wave = tid >> 6, lane = tid & 63;
    int q = lane & 15, g = lane >> 4;
    int c = cnt[w]; if (c > 192) c = 192;
    int T = 64 + c;
    {
        int t = tid;
        if (t < T) {
            int tok;
            if (t < 64) tok = b * 4096 + (wy * 8 + (t >> 3)) * 64 + wx * 8 + (t & 7);
            else        tok = 8192 + wpts[w * 192 + t - 64];
            const unsigned short* base = qkv + (size_t)tok * 384 + h * 16;
            bf16x8 k0 = *(const bf16x8*)(base + 128);
            bf16x8 v0 = *(const bf16x8*)(base + 256);
            *(bf16x8*)&Kl[t][0] = k0;
#pragma unroll
            for (int d = 0; d < 8; ++d) Vt[d][t] = (unsigned short)v0[d];
            bf16x8 k1 = *(const bf16x8*)(base + 136);
            bf16x8 v1 = *(const bf16x8*)(base + 264);
            *(bf16x8*)&Kl[t][8] = k1;
#pragma unroll
            for (int d = 0; d < 8; ++d) Vt[8 + d][t] = (unsigned short)v1[d];
        } else {
            bf16x8 z;
#pragma unroll
            for (int d = 0; d < 8; ++d) z[d] = 0;
            *(bf16x8*)&Kl[t][0] = z;
            *(bf16x8*)&Kl[t][8] = z;
#pragma unroll
            for (int d = 0; d < 16; ++d) Vt[d][t] = 0;
        }
    }
    int qq = wave * 16 + q;
    int qrow = b * 4096 + (wy * 8 + (qq >> 3)) * 64 + wx * 8 + (qq & 7);
    bf16x8 qfrag;
#pragma unroll
    for (int j = 0; j < 8; ++j) qfrag[j] = 0;
    if (g < 2) qfrag = *(const bf16x8*)(qkv + (size_t)qrow * 384 + h * 16 + g * 8);

    __syncthreads();

    float p[16][4];
    int MT = (T + 15) >> 4;
#pragma unroll
    for (int mt = 0; mt < 16; ++mt) {
        if (mt < MT) {
            bf16x8 af = *(const bf16x8*)&Kl[mt * 16 + q][(g & 1) * 8];
            f32x4 cc = (f32x4){0.f, 0.f, 0.f, 0.f};
            cc = __builtin_amdgcn_mfma_f32_16x16x32_bf16(af, qfrag, cc, 0, 0, 0);
#pragma unroll
            for (int r = 0; r < 4; ++r) {
                int tok = mt * 16 + g * 4 + r;
                p[mt][r] = (tok < T) ? cc[r] * 0.25f : -1e30f;
            }
        } else {
#pragma unroll
            for (int r = 0; r < 4; ++r) p[mt][r] = -1e30f;
        }
    }
    float mv = -3.0e38f;
#pragma unroll
    for (int mt = 0; mt < 16; ++mt)
#pragma unroll
        for (int r = 0; r < 4; ++r) mv = fmaxf(mv, p[mt][r]);
    mv = fmaxf(mv, __shfl_xor(mv, 16));
    mv = fmaxf(mv, __shfl_xor(mv, 32));
    float ls = 0.f;
#pragma unroll
    for (int mt = 0; mt < 16; ++mt)
#pragma unroll
        for (int r = 0; r < 4; ++r) {
            float e = __expf(p[mt][r] - mv);
            p[mt][r] = e;
            ls += e;
        }
    ls += __shfl_xor(ls, 16);
    ls += __shfl_xor(ls, 32);

    f32x4 oacc = (f32x4){0.f, 0.f, 0.f, 0.f};
    int KS = (T + 31) >> 5;
    int srcA = q + (((2 * g) & 3) << 4);
    int srcB = q + (((2 * g + 1) & 3) << 4);
#pragma unroll
    for (int ks = 0; ks < 8; ++ks) {
        if (ks < KS) {
            int n0lo, n0hi, n1lo, n1hi;
            asm("v_cvt_pk_bf16_f32 %0, %1, %2" : "=v"(n0lo) : "v"(p[2 * ks][0]), "v"(p[2 * ks][1]));
            asm("v_cvt_pk_bf16_f32 %0, %1, %2" : "=v"(n0hi) : "v"(p[2 * ks][2]), "v"(p[2 * ks][3]));
            asm("v_cvt_pk_bf16_f32 %0, %1, %2" : "=v"(n1lo) : "v"(p[2 * ks + 1][0]), "v"(p[2 * ks + 1][1]));
            asm("v_cvt_pk_bf16_f32 %0, %1, %2" : "=v"(n1hi) : "v"(p[2 * ks + 1][2]), "v"(p[2 * ks + 1][3]));
            int a0 = __shfl(n0lo, srcA), b0 = __shfl(n1lo, srcA);
            int a1 = __shfl(n0hi, srcA), b1 = __shfl(n1hi, srcA);
            int a2 = __shfl(n0lo, srcB), b2 = __shfl(n1lo, srcB);
            int a3 = __shfl(n0hi, srcB), b3 = __shfl(n1hi, srcB);
            union { int d[4]; bf16x8 v; } pb;
            bool lo2 = (g < 2);
            pb.d[0] = lo2 ? a0 : b0;
            pb.d[1] = lo2 ? a1 : b1;
            pb.d[2] = lo2 ? a2 : b2;
            pb.d[3] = lo2 ? a3 : b3;
            bf16x8 vf = *(const bf16x8*)&Vt[q][ks * 32 + g * 8];
            oacc = __builtin_amdgcn_mfma_f32_16x16x32_bf16(vf, pb.v, oacc, 0, 0, 0);
        }
    }
    float inv = 1.0f / ls;
    ushort4 st;
    st.x = f2b(oacc[0] * inv);
    st.y = f2b(oacc[1] * inv);
    st.z = f2b(oacc[2] * inv);
    st.w = f2b(oacc[3] * inv);
    *(ushort4*)(aout + (size_t)qrow * 128 + h * 16 + g * 4) = st;
}

// ---------------- fused tail: proj GEMM + RK4 ODE + residual + conv_out (col-split) ----------
// 512 blocks x 128 thr; block = ONE 16-row tile, its 2 waves split the N dimension
// (wave owns tn = wave*4..wave*4+3 of the D=128 state; conv_out: 8 of 16 ch tiles).
// Full-row K dependency via shared double-buffered tc (one barrier per phase; WAR-safe
// because each buffer's readers pass >=1 barrier before that buffer is rewritten).
__global__ __launch_bounds__(128) void tail_k(const unsigned short* __restrict__ aout,
                                              const unsigned short* __restrict__ pwb,
                                              const float* __restrict__ pb,
                                              const unsigned short* __restrict__ owb,
                                              const float* __restrict__ ob,
                                              const unsigned short* __restrict__ cwb,
                                              const float* __restrict__ cb,
                                              float* __restrict__ outp) {
    __shared__ unsigned short Wl[128][136];
    __shared__ unsigned short tc[2][16][136];
    int tid = threadIdx.x, wave = tid >> 6, lane = tid & 63;
    int g = lane >> 4, q = lane & 15;
    {
        int part = tid & 15;
#pragma unroll
        for (int it = 0; it < 16; ++it) {
            int rr = (tid >> 4) + it * 8;
            *(bf16x8*)&Wl[rr][part * 8] = *(const bf16x8*)(owb + rr * 128 + part * 8);
        }
    }
    int R0 = blockIdx.x * 16;
    int tnb = wave * 4;

    // ---- phase A: proj GEMM -> y0 (this wave's 4 tn tiles, C-frag layout) ----
    float y0[16];
    {
        const unsigned short* Arow = aout + (size_t)(R0 + q) * 128;
        f32x4 pacc[4];
#pragma unroll
        for (int t4 = 0; t4 < 4; ++t4) pacc[t4] = (f32x4){0.f, 0.f, 0.f, 0.f};
#pragma unroll
        for (int k0 = 0; k0 < 128; k0 += 32) {
            bf16x8 a = *(const bf16x8*)(Arow + k0 + g * 8);
#pragma unroll
            for (int t4 = 0; t4 < 4; ++t4) {
                bf16x8 bfr = *(const bf16x8*)(pwb + (size_t)((tnb + t4) * 16 + q) * 128 + k0 + g * 8);
                pacc[t4] = __builtin_amdgcn_mfma_f32_16x16x32_bf16(a, bfr, pacc[t4], 0, 0, 0);
            }
        }
#pragma unroll
        for (int t4 = 0; t4 < 4; ++t4) {
            float bsv = pb[(tnb + t4) * 16 + q];
#pragma unroll
            for (int rr = 0; rr < 4; ++rr) y0[t4 * 4 + rr] = pacc[t4][rr] + bsv;
        }
    }

    float bs[4];
#pragma unroll
    for (int t4 = 0; t4 < 4; ++t4) bs[t4] = ob[(tnb + t4) * 16 + q];
    float y[16], ac[16], ko[16];
#pragma unroll
    for (int i = 0; i < 16; ++i) y[i] = y0[i];

#define WRITE_TC(BUF, EXPR)                                               \
    {                                                                     \
        _Pragma("unroll")                                                 \
        for (int t4 = 0; t4 < 4; ++t4) {                                  \
            _Pragma("unroll")                                             \
            for (int rr = 0; rr < 4; ++rr) {                              \
                int i_ = t4 * 4 + rr;                                     \
                tc[BUF][g * 4 + rr][(tnb + t4) * 16 + q] = f2b(EXPR);     \
            }                                                             \
        }                                                                 \
        __syncthreads();                                                  \
    }

#define EVAL(BUF)                                                                      \
    {                                                                                  \
        bf16x8 af[4];                                                                  \
        _Pragma("unroll")                                                              \
        for (int tk = 0; tk < 4; ++tk)                                                 \
            af[tk] = *(const bf16x8*)&tc[BUF][q][tk * 32 + g * 8];                     \
        _Pragma("unroll")                                                              \
        for (int t4 = 0; t4 < 4; ++t4) {                                               \
            f32x4 cc = (f32x4){0.f, 0.f, 0.f, 0.f};                                    \
            _Pragma("unroll")                                                          \
            for (int tk = 0; tk < 4; ++tk) {                                           \
                bf16x8 bfr = *(const bf16x8*)&Wl[(tnb + t4) * 16 + q][tk * 32 + g * 8];\
                cc = __builtin_amdgcn_mfma_f32_16x16x32_bf16(af[tk], bfr, cc, 0, 0, 0);\
            }                                                                          \
            _Pragma("unroll")                                                          \
            for (int rr = 0; rr < 4; ++rr)                                             \
                ko[t4 * 4 + rr] = fmaxf(cc[rr] + bs[t4], 0.f);                         \
        }                                                                              \
    }

    WRITE_TC(0, y[i_])
    const float dt = 0.25f;
    for (int st = 0; st < 4; ++st) {
        EVAL(0);
#pragma unroll
        for (int i = 0; i < 16; ++i) ac[i] = y[i] + (dt / 6.f) * ko[i];
        WRITE_TC(1, y[i_] + (0.5f * dt) * ko[i_])
        EVAL(1);
#pragma unroll
        for (int i = 0; i < 16; ++i) ac[i] += (dt / 3.f) * ko[i];
        WRITE_TC(0, y[i_] + (0.5f * dt) * ko[i_])
        EVAL(0);
#pragma unroll
        for (int i = 0; i < 16; ++i) ac[i] += (dt / 3.f) * ko[i];
        WRITE_TC(1, y[i_] + dt * ko[i_])
        EVAL(1);
#pragma unroll
        for (int i = 0; i < 16; ++i) y[i] = ac[i] + (dt / 6.f) * ko[i];
        WRITE_TC(0, y[i_])
    }

    // ---- phase C: residual + conv_out (wave owns 8 of 16 channel tiles) ----
    WRITE_TC(1, y[i_] + y0[i_])
    {
        int p = R0 + g * 4;
        int bb = p >> 12, plo = p & 4095;
#pragma unroll
        for (int t2 = 0; t2 < 8; ++t2) {
            int tn2 = wave * 8 + t2;
            f32x4 cc = (f32x4){0.f, 0.f, 0.f, 0.f};
#pragma unroll
            for (int tk = 0; tk < 4; ++tk) {
                bf16x8 af = *(const bf16x8*)&tc[1][q][tk * 32 + g * 8];
                bf16x8 bfr = *(const bf16x8*)(cwb + (size_t)(tn2 * 16 + q) * 128 + tk * 32 + g * 8);
                cc = __builtin_amdgcn_mfma_f32_16x16x32_bf16(af, bfr, cc, 0, 0, 0);
            }
            int ch = tn2 * 16 + q;
            float bsv = cb[ch];
            float4 stv;
            stv.x = cc[0] + bsv;
            stv.y = cc[1] + bsv;
            stv.z = cc[2] + bsv;
            stv.w = cc[3] + bsv;
            *(float4*)(outp + ((size_t)(bb * 256 + ch)) * 4096 + plo) = stv;
        }
    }
#undef WRITE_TC
#undef EVAL
}

extern "C" void kernel_launch(void* const* d_in, const int* in_sizes, int n_in,
                              void* d_out, int out_size, void* d_ws, size_t ws_size,
                              hipStream_t stream) {
    (void)in_sizes; (void)n_in; (void)out_size; (void)ws_size;
    const float* img_in = (const float*)d_in[0];
    const int*   pts_uv = (const int*)d_in[1];
    const float* ptsf   = (const float*)d_in[2];
    const float* ciw    = (const float*)d_in[3];
    const float* cib    = (const float*)d_in[4];
    const float* qw     = (const float*)d_in[5];
    const float* qb     = (const float*)d_in[6];
    const float* pw     = (const float*)d_in[7];
    const float* pb     = (const float*)d_in[8];
    const float* ow     = (const float*)d_in[9];
    const float* ob     = (const float*)d_in[10];
    const float* cw     = (const float*)d_in[11];
    const float* cb     = (const float*)d_in[12];

    char* ws = (char*)d_ws;
    unsigned short* feat = (unsigned short*)(ws);                 // [0,        2097152)  8192x128 bf16
    unsigned short* qkv  = (unsigned short*)(ws + 2097152);       // [2097152, 14680064)  16384x384 bf16
    unsigned short* aout = (unsigned short*)(ws + 14680064);      // [14680064,16777216)  8192x128 bf16
    int*            cnt  = (int*)(ws + 16777216);                 // [16777216,16777728)  128 ints
    int*            wpts = (int*)(ws + 16777728);                 // [16777728,16876032)  128x192 ints
    unsigned short* wb   = (unsigned short*)(ws + 16876544);      // [16876544,17171456)  bf16 weights
    unsigned short* ciw_b = wb;
    unsigned short* qw_b  = wb + 32768;
    unsigned short* pw_b  = wb + 81920;
    unsigned short* ow_b  = wb + 98304;
    unsigned short* cw_b  = wb + 114688;

    cast_k<<<576, 256, 0, stream>>>(ciw, qw, pw, ow, cw, wb, cnt);
    assign_k<<<32, 256, 0, stream>>>(pts_uv, cnt, wpts);
    cin_k<<<128, 256, 0, stream>>>(img_in, ciw_b, cib, feat);
    qkv_k<<<dim3(256, 6), 256, 0, stream>>>(feat, ptsf, qw_b, qb, qkv);
    attn_k<<<1024, 256, 0, stream>>>(qkv, cnt, wpts, aout);
    tail_k<<<512, 128, 0, stream>>>(aout, pw_b, pb, ow_b, ob, cw_b, cb, (float*)d_out);
}

// Round 14
// 148.476 us; speedup vs baseline: 1.1505x; 1.0331x over previous
//
#include <hip/hip_runtime.h>

typedef short bf16x8 __attribute__((ext_vector_type(8)));
typedef float f32x4 __attribute__((ext_vector_type(4)));

__device__ __forceinline__ float b2f(unsigned short s) {
    union { float f; unsigned u; } x; x.u = ((unsigned)s) << 16; return x.f;
}
__device__ __forceinline__ unsigned short f2b(float f) {
    unsigned u = __float_as_uint(f);
    unsigned r = (u + 0x7fffu + ((u >> 16) & 1u)) >> 16;
    return (unsigned short)r;
}

// ---------------- cast f32 weights -> bf16 workspace; zero window counters ----------------
// dst layout: [ciw 32768][qw 49152][pw 16384][ow 16384][cw 32768]  (147456 = 576*256)
__global__ __launch_bounds__(256) void cast_k(const float* __restrict__ ciw,
                                              const float* __restrict__ qw,
                                              const float* __restrict__ pw,
                                              const float* __restrict__ ow,
                                              const float* __restrict__ cw,
                                              unsigned short* __restrict__ dst,
                                              int* __restrict__ cnt) {
    if (blockIdx.x == 0 && threadIdx.x < 128) cnt[threadIdx.x] = 0;
    int i = blockIdx.x * 256 + threadIdx.x;
    float v;
    if (i < 32768)        v = ciw[i];
    else if (i < 81920)   v = qw[i - 32768];
    else if (i < 98304)   v = pw[i - 81920];
    else if (i < 114688)  v = ow[i - 98304];
    else                  v = cw[i - 114688];
    dst[i] = f2b(v);
}

// ---------------- window bookkeeping ----------------
__global__ __launch_bounds__(256) void assign_k(const int* __restrict__ uv,
                                                int* __restrict__ cnt,
                                                int* __restrict__ wpts) {
    int i = blockIdx.x * 256 + threadIdx.x;
    if (i >= 8192) return;
    int b = uv[3 * i] & 1;
    int u = uv[3 * i + 1] & 63;
    int v = uv[3 * i + 2] & 63;
    int w = b * 64 + ((v >> 3) << 3) + (u >> 3);
    int slot = atomicAdd(cnt + w, 1);
    if (slot < 192) wpts[w * 192 + slot] = i;
}

// ---------------- fused conv_in + qkv (pixel rows): transpose -> conv -> qkv, no global feat ----
// 256 blocks x 128 thr (2 waves), 32 pixels/block. At/ft live in LDS only.
// Numerics identical to the old cin_k->feat->qkv_k chain (same f2b rounding points).
__global__ __launch_bounds__(128) void cinqkv_k(const float* __restrict__ in,
                                                const unsigned short* __restrict__ ciwb,
                                                const float* __restrict__ cib,
                                                const unsigned short* __restrict__ qwb,
                                                const float* __restrict__ qb,
                                                unsigned short* __restrict__ qkv) {
    __shared__ unsigned short At[32][264];   // [px][ch], 528B rows (16B-aligned)
    __shared__ unsigned short ft[32][136];   // [px][d],  272B rows (16B-aligned)
    int p0 = blockIdx.x * 32, b = p0 >> 12, hw0 = p0 & 4095;
    int tid = threadIdx.x, wave = tid >> 6, lane = tid & 63;
    // stage+cast+transpose: 128 threads, lane group = px (coalesced global reads)
    {
        int px = tid & 31, chq = tid >> 5;  // 4 ch rows per pass
#pragma unroll
        for (int i = 0; i < 64; ++i) {
            int c = chq + i * 4;
            At[px][c] = f2b(in[((size_t)(b * 256 + c)) * 4096 + hw0 + px]);
        }
    }
    __syncthreads();
    int q = lane & 15, g = lane >> 4;
    int m0 = wave * 16;
    // conv_in GEMM: 16 px rows x 128 outputs, K=256
    {
        f32x4 acc[8];
#pragma unroll
        for (int tn = 0; tn < 8; ++tn) acc[tn] = (f32x4){0.f, 0.f, 0.f, 0.f};
#pragma unroll
        for (int k0 = 0; k0 < 256; k0 += 32) {
            bf16x8 a = *(const bf16x8*)&At[m0 + q][k0 + g * 8];
#pragma unroll
            for (int tn = 0; tn < 8; ++tn) {
                bf16x8 bfr = *(const bf16x8*)(ciwb + (size_t)(tn * 16 + q) * 256 + k0 + g * 8);
                acc[tn] = __builtin_amdgcn_mfma_f32_16x16x32_bf16(a, bfr, acc[tn], 0, 0, 0);
            }
        }
#pragma unroll
        for (int tn = 0; tn < 8; ++tn) {
            int n = tn * 16 + q;
            float bs = cib[n];
#pragma unroll
            for (int rr = 0; rr < 4; ++rr)
                ft[m0 + g * 4 + rr][n] = f2b(acc[tn][rr] + bs);
        }
    }
    __syncthreads();
    // qkv GEMM: same 16 px rows x 384 outputs, K=128, A from ft
    {
        bf16x8 af[4];
#pragma unroll
        for (int tk = 0; tk < 4; ++tk)
            af[tk] = *(const bf16x8*)&ft[m0 + q][tk * 32 + g * 8];
#pragma unroll
        for (int tt = 0; tt < 24; ++tt) {
            f32x4 cc = (f32x4){0.f, 0.f, 0.f, 0.f};
#pragma unroll
            for (int tk = 0; tk < 4; ++tk) {
                bf16x8 bfr = *(const bf16x8*)(qwb + (size_t)(tt * 16 + q) * 128 + tk * 32 + g * 8);
                cc = __builtin_amdgcn_mfma_f32_16x16x32_bf16(af[tk], bfr, cc, 0, 0, 0);
            }
            int n = tt * 16 + q;
            float bsv = qb[n];
#pragma unroll
            for (int rr = 0; rr < 4; ++rr)
                qkv[(size_t)(p0 + m0 + g * 4 + rr) * 384 + n] = f2b(cc[rr] + bsv);
        }
    }
}

// ---------------- qkv for point rows (K/V columns only; Q of points is never read) ----------
// grid (128, 4): bx -> 64 point rows, by -> nb = 128 + by*64.
__global__ __launch_bounds__(256) void ptqkv_k(const float* __restrict__ ptsf,
                                               const unsigned short* __restrict__ Wm,
                                               const float* __restrict__ bias,
                                               unsigned short* __restrict__ qkv) {
    int lane = threadIdx.x & 63, wv = threadIdx.x >> 6;
    int row = (blockIdx.x * 4 + wv) * 16;           // point-local row base
    int q = lane & 15, g = lane >> 4;
    int nb = 128 + blockIdx.y * 64, koff = g * 8;
    f32x4 acc[4];
#pragma unroll
    for (int tt = 0; tt < 4; ++tt) acc[tt] = (f32x4){0.f, 0.f, 0.f, 0.f};
#pragma unroll
    for (int k0 = 0; k0 < 128; k0 += 32) {
        const float* pr = ptsf + (size_t)(row + q) * 128 + k0 + koff;
        float4 f0 = *(const float4*)pr;
        float4 f1 = *(const float4*)(pr + 4);
        bf16x8 a;
        a[0] = (short)f2b(f0.x); a[1] = (short)f2b(f0.y);
        a[2] = (short)f2b(f0.z); a[3] = (short)f2b(f0.w);
        a[4] = (short)f2b(f1.x); a[5] = (short)f2b(f1.y);
        a[6] = (short)f2b(f1.z); a[7] = (short)f2b(f1.w);
#pragma unroll
        for (int tt = 0; tt < 4; ++tt) {
            bf16x8 bfr = *(const bf16x8*)(Wm + (size_t)(nb + tt * 16 + q) * 128 + k0 + koff);
            acc[tt] = __builtin_amdgcn_mfma_f32_16x16x32_bf16(a, bfr, acc[tt], 0, 0, 0);
        }
    }
#pragma unroll
    for (int tt = 0; tt < 4; ++tt) {
        int n = nb + tt * 16 + q;
        float bs = bias[n];
#pragma unroll
        for (int rr = 0; rr < 4; ++rr)
            qkv[(size_t)(8192 + row + g * 4 + rr) * 384 + n] = f2b(acc[tt][rr] + bs);
    }
}

// ---------------- MFMA windowed attention (verified round 6) ----------------
__global__ __launch_bounds__(256) void attn_k(const unsigned short* __restrict__ qkv,
                                              const int* __restrict__ cnt,
                                              const int* __restrict__ wpts,
                                              unsigned short* __restrict__ aout) {
    __shared__ unsigned short Kl[256][24];
    __shared__ unsigned short Vt[16][264];
    int blk = blockIdx.x;
    int w = blk >> 3, h = blk & 7;
    int b = w >> 6, wy = (w >> 3) & 7, wx = w & 7;
    int tid = threadIdx.x, wave = tid >> 6, lane = tid & 63;
    int q = lane & 15, g = lane >> 4;
    int c = cnt[w]; if (c > 192) c = 192;
    int T = 64 + c;
    {
        int t = tid;
        if (t < T) {
            int tok;
            if (t < 64) tok = b * 4096 + (wy * 8 + (t >> 3)) * 64 + wx * 8 + (t & 7);
            else        tok = 8192 + wpts[w * 192 + t - 64];
            const unsigned short* base = qkv + (size_t)tok * 384 + h * 16;
            bf16x8 k0 = *(const bf16x8*)(base + 128);
            bf16x8 v0 = *(const bf16x8*)(base + 256);
            *(bf16x8*)&Kl[t][0] = k0;
#pragma unroll
            for (int d = 0; d < 8; ++d) Vt[d][t] = (unsigned short)v0[d];
            bf16x8 k1 = *(const bf16x8*)(base + 136);
            bf16x8 v1 = *(const bf16x8*)(base + 264);
            *(bf16x8*)&Kl[t][8] = k1;
#pragma unroll
            for (int d = 0; d < 8; ++d) Vt[8 + d][t] = (unsigned short)v1[d];
        } else {
            bf16x8 z;
#pragma unroll
            for (int d = 0; d < 8; ++d) z[d] = 0;
            *(bf16x8*)&Kl[t][0] = z;
            *(bf16x8*)&Kl[t][8] = z;
#pragma unroll
            for (int d = 0; d < 16; ++d) Vt[d][t] = 0;
        }
    }
    int qq = wave * 16 + q;
    int qrow = b * 4096 + (wy * 8 + (qq >> 3)) * 64 + wx * 8 + (qq & 7);
    bf16x8 qfrag;
#pragma unroll
    for (int j = 0; j < 8; ++j) qfrag[j] = 0;
    if (g < 2) qfrag = *(const bf16x8*)(qkv + (size_t)qrow * 384 + h * 16 + g * 8);

    __syncthreads();

    float p[16][4];
    int MT = (T + 15) >> 4;
#pragma unroll
    for (int mt = 0; mt < 16; ++mt) {
        if (mt < MT) {
            bf16x8 af = *(const bf16x8*)&Kl[mt * 16 + q][(g & 1) * 8];
            f32x4 cc = (f32x4){0.f, 0.f, 0.f, 0.f};
            cc = __builtin_amdgcn_mfma_f32_16x16x32_bf16(af, qfrag, cc, 0, 0, 0);
#pragma unroll
            for (int r = 0; r < 4; ++r) {
                int tok = mt * 16 + g * 4 + r;
                p[mt][r] = (tok < T) ? cc[r] * 0.25f : -1e30f;
            }
        } else {
#pragma unroll
            for (int r = 0; r < 4; ++r) p[mt][r] = -1e30f;
        }
    }
    float mv = -3.0e38f;
#pragma unroll
    for (int mt = 0; mt < 16; ++mt)
#pragma unroll
        for (int r = 0; r < 4; ++r) mv = fmaxf(mv, p[mt][r]);
    mv = fmaxf(mv, __shfl_xor(mv, 16));
    mv = fmaxf(mv, __shfl_xor(mv, 32));
    float ls = 0.f;
#pragma unroll
    for (int mt = 0; mt < 16; ++mt)
#pragma unroll
        for (int r = 0; r < 4; ++r) {
            float e = __expf(p[mt][r] - mv);
            p[mt][r] = e;
            ls += e;
        }
    ls += __shfl_xor(ls, 16);
    ls += __shfl_xor(ls, 32);

    f32x4 oacc = (f32x4){0.f, 0.f, 0.f, 0.f};
    int KS = (T + 31) >> 5;
    int srcA = q + (((2 * g) & 3) << 4);
    int srcB = q + (((2 * g + 1) & 3) << 4);
#pragma unroll
    for (int ks = 0; ks < 8; ++ks) {
        if (ks < KS) {
            int n0lo, n0hi, n1lo, n1hi;
            asm("v_cvt_pk_bf16_f32 %0, %1, %2" : "=v"(n0lo) : "v"(p[2 * ks][0]), "v"(p[2 * ks][1]));
            asm("v_cvt_pk_bf16_f32 %0, %1, %2" : "=v"(n0hi) : "v"(p[2 * ks][2]), "v"(p[2 * ks][3]));
            asm("v_cvt_pk_bf16_f32 %0, %1, %2" : "=v"(n1lo) : "v"(p[2 * ks + 1][0]), "v"(p[2 * ks + 1][1]));
            asm("v_cvt_pk_bf16_f32 %0, %1, %2" : "=v"(n1hi) : "v"(p[2 * ks + 1][2]), "v"(p[2 * ks + 1][3]));
            int a0 = __shfl(n0lo, srcA), b0 = __shfl(n1lo, srcA);
            int a1 = __shfl(n0hi, srcA), b1 = __shfl(n1hi, srcA);
            int a2 = __shfl(n0lo, srcB), b2 = __shfl(n1lo, srcB);
            int a3 = __shfl(n0hi, srcB), b3 = __shfl(n1hi, srcB);
            union { int d[4]; bf16x8 v; } pb;
            bool lo2 = (g < 2);
            pb.d[0] = lo2 ? a0 : b0;
            pb.d[1] = lo2 ? a1 : b1;
            pb.d[2] = lo2 ? a2 : b2;
            pb.d[3] = lo2 ? a3 : b3;
            bf16x8 vf = *(const bf16x8*)&Vt[q][ks * 32 + g * 8];
            oacc = __builtin_amdgcn_mfma_f32_16x16x32_bf16(vf, pb.v, oacc, 0, 0, 0);
        }
    }
    float inv = 1.0f / ls;
    ushort4 st;
    st.x = f2b(oacc[0] * inv);
    st.y = f2b(oacc[1] * inv);
    st.z = f2b(oacc[2] * inv);
    st.w = f2b(oacc[3] * inv);
    *(ushort4*)(aout + (size_t)qrow * 128 + h * 16 + g * 4) = st;
}

// ---------------- fused tail: proj GEMM + RK4 ODE + residual + conv_out (col-split) ----------
// 512 blocks x 128 thr; block = ONE 16-row tile, its 2 waves split the N dimension.
// Full-row K dependency via shared double-buffered tc (verified round 11).
__global__ __launch_bounds__(128) void tail_k(const unsigned short* __restrict__ aout,
                                              const unsigned short* __restrict__ pwb,
                                              const float* __restrict__ pb,
                                              const unsigned short* __restrict__ owb,
                                              const float* __restrict__ ob,
                                              const unsigned short* __restrict__ cwb,
                                              const float* __restrict__ cb,
                                              float* __restrict__ outp) {
    __shared__ unsigned short Wl[128][136];
    __shared__ unsigned short tc[2][16][136];
    int tid = threadIdx.x, wave = tid >> 6, lane = tid & 63;
    int g = lane >> 4, q = lane & 15;
    {
        int part = tid & 15;
#pragma unroll
        for (int it = 0; it < 16; ++it) {
            int rr = (tid >> 4) + it * 8;
            *(bf16x8*)&Wl[rr][part * 8] = *(const bf16x8*)(owb + rr * 128 + part * 8);
        }
    }
    int R0 = blockIdx.x * 16;
    int tnb = wave * 4;

    float y0[16];
    {
        const unsigned short* Arow = aout + (size_t)(R0 + q) * 128;
        f32x4 pacc[4];
#pragma unroll
        for (int t4 = 0; t4 < 4; ++t4) pacc[t4] = (f32x4){0.f, 0.f, 0.f, 0.f};
#pragma unroll
        for (int k0 = 0; k0 < 128; k0 += 32) {
            bf16x8 a = *(const bf16x8*)(Arow + k0 + g * 8);
#pragma unroll
            for (int t4 = 0; t4 < 4; ++t4) {
                bf16x8 bfr = *(const bf16x8*)(pwb + (size_t)((tnb + t4) * 16 + q) * 128 + k0 + g * 8);
                pacc[t4] = __builtin_amdgcn_mfma_f32_16x16x32_bf16(a, bfr, pacc[t4], 0, 0, 0);
            }
        }
#pragma unroll
        for (int t4 = 0; t4 < 4; ++t4) {
            float bsv = pb[(tnb + t4) * 16 + q];
#pragma unroll
            for (int rr = 0; rr < 4; ++rr) y0[t4 * 4 + rr] = pacc[t4][rr] + bsv;
        }
    }

    float bs[4];
#pragma unroll
    for (int t4 = 0; t4 < 4; ++t4) bs[t4] = ob[(tnb + t4) * 16 + q];
    float y[16], ac[16], ko[16];
#pragma unroll
    for (int i = 0; i < 16; ++i) y[i] = y0[i];

#define WRITE_TC(BUF, EXPR)                                               \
    {                                                                     \
        _Pragma("unroll")                                                 \
        for (int t4 = 0; t4 < 4; ++t4) {                                  \
            _Pragma("unroll")                                             \
            for (int rr = 0; rr < 4; ++rr) {                              \
                int i_ = t4 * 4 + rr;                                     \
                tc[BUF][g * 4 + rr][(tnb + t4) * 16 + q] = f2b(EXPR);     \
            }                                                             \
        }                                                                 \
        __syncthreads();                                                  \
    }

#define EVAL(BUF)                                                                      \
    {                                                                                  \
        bf16x8 af[4];                                                                  \
        _Pragma("unroll")                                                              \
        for (int tk = 0; tk < 4; ++tk)                                                 \
            af[tk] = *(const bf16x8*)&tc[BUF][q][tk * 32 + g * 8];                     \
        _Pragma("unroll")                                                              \
        for (int t4 = 0; t4 < 4; ++t4) {                                               \
            f32x4 cc = (f32x4){0.f, 0.f, 0.f, 0.f};                                    \
            _Pragma("unroll")                                                          \
            for (int tk = 0; tk < 4; ++tk) {                                           \
                bf16x8 bfr = *(const bf16x8*)&Wl[(tnb + t4) * 16 + q][tk * 32 + g * 8];\
                cc = __builtin_amdgcn_mfma_f32_16x16x32_bf16(af[tk], bfr, cc, 0, 0, 0);\
            }                                                                          \
            _Pragma("unroll")                                                          \
            for (int rr = 0; rr < 4; ++rr)                                             \
                ko[t4 * 4 + rr] = fmaxf(cc[rr] + bs[t4], 0.f);                         \
        }                                                                              \
    }

    WRITE_TC(0, y[i_])
    const float dt = 0.25f;
    for (int st = 0; st < 4; ++st) {
        EVAL(0);
#pragma unroll
        for (int i = 0; i < 16; ++i) ac[i] = y[i] + (dt / 6.f) * ko[i];
        WRITE_TC(1, y[i_] + (0.5f * dt) * ko[i_])
        EVAL(1);
#pragma unroll
        for (int i = 0; i < 16; ++i) ac[i] += (dt / 3.f) * ko[i];
        WRITE_TC(0, y[i_] + (0.5f * dt) * ko[i_])
        EVAL(0);
#pragma unroll
        for (int i = 0; i < 16; ++i) ac[i] += (dt / 3.f) * ko[i];
        WRITE_TC(1, y[i_] + dt * ko[i_])
        EVAL(1);
#pragma unroll
        for (int i = 0; i < 16; ++i) y[i] = ac[i] + (dt / 6.f) * ko[i];
        WRITE_TC(0, y[i_])
    }

    WRITE_TC(1, y[i_] + y0[i_])
    {
        int p = R0 + g * 4;
        int bb = p >> 12, plo = p & 4095;
#pragma unroll
        for (int t2 = 0; t2 < 8; ++t2) {
            int tn2 = wave * 8 + t2;
            f32x4 cc = (f32x4){0.f, 0.f, 0.f, 0.f};
#pragma unroll
            for (int tk = 0; tk < 4; ++tk) {
                bf16x8 af = *(const bf16x8*)&tc[1][q][tk * 32 + g * 8];
                bf16x8 bfr = *(const bf16x8*)(cwb + (size_t)(tn2 * 16 + q) * 128 + tk * 32 + g * 8);
                cc = __builtin_amdgcn_mfma_f32_16x16x32_bf16(af, bfr, cc, 0, 0, 0);
            }
            int ch = tn2 * 16 + q;
            float bsv = cb[ch];
            float4 stv;
            stv.x = cc[0] + bsv;
            stv.y = cc[1] + bsv;
            stv.z = cc[2] + bsv;
            stv.w = cc[3] + bsv;
            *(float4*)(outp + ((size_t)(bb * 256 + ch)) * 4096 + plo) = stv;
        }
    }
#undef WRITE_TC
#undef EVAL
}

extern "C" void kernel_launch(void* const* d_in, const int* in_sizes, int n_in,
                              void* d_out, int out_size, void* d_ws, size_t ws_size,
                              hipStream_t stream) {
    (void)in_sizes; (void)n_in; (void)out_size; (void)ws_size;
    const float* img_in = (const float*)d_in[0];
    const int*   pts_uv = (const int*)d_in[1];
    const float* ptsf   = (const float*)d_in[2];
    const float* ciw    = (const float*)d_in[3];
    const float* cib    = (const float*)d_in[4];
    const float* qw     = (const float*)d_in[5];
    const float* qb     = (const float*)d_in[6];
    const float* pw     = (const float*)d_in[7];
    const float* pb     = (const float*)d_in[8];
    const float* ow     = (const float*)d_in[9];
    const float* ob     = (const float*)d_in[10];
    const float* cw     = (const float*)d_in[11];
    const float* cb     = (const float*)d_in[12];

    char* ws = (char*)d_ws;
    unsigned short* qkv  = (unsigned short*)(ws + 2097152);       // [2097152, 14680064)  16384x384 bf16
    unsigned short* aout = (unsigned short*)(ws + 14680064);      // [14680064,16777216)  8192x128 bf16
    int*            cnt  = (int*)(ws + 16777216);                 // [16777216,16777728)  128 ints
    int*            wpts = (int*)(ws + 16777728);                 // [16777728,16876032)  128x192 ints
    unsigned short* wb   = (unsigned short*)(ws + 16876544);      // [16876544,17171456)  bf16 weights
    unsigned short* ciw_b = wb;
    unsigned short* qw_b  = wb + 32768;
    unsigned short* pw_b  = wb + 81920;
    unsigned short* ow_b  = wb + 98304;
    unsigned short* cw_b  = wb + 114688;

    cast_k<<<576, 256, 0, stream>>>(ciw, qw, pw, ow, cw, wb, cnt);
    assign_k<<<32, 256, 0, stream>>>(pts_uv, cnt, wpts);
    cinqkv_k<<<256, 128, 0, stream>>>(img_in, ciw_b, cib, qw_b, qb, qkv);
    ptqkv_k<<<dim3(128, 4), 256, 0, stream>>>(ptsf, qw_b, qb, qkv);
    attn_k<<<1024, 256, 0, stream>>>(qkv, cnt, wpts, aout);
    tail_k<<<512, 128, 0, stream>>>(aout, pw_b, pb, ow_b, ob, cw_b, cb, (float*)d_out);
}